// Round 13
// baseline (228.310 us; speedup 1.0000x reference)
//
#include <hip/hip_runtime.h>
#include <hip/hip_fp8.h>

#define S_LEN 512
#define BATCH 256
#define L 128
#define PAD_ID 0
#define START_ID 1

typedef int    i32x8 __attribute__((ext_vector_type(8)));
typedef int    i32x4 __attribute__((ext_vector_type(4)));
typedef float  f32x4 __attribute__((ext_vector_type(4)));
typedef unsigned int   u32x4 __attribute__((ext_vector_type(4)));
typedef unsigned short u16x2 __attribute__((ext_vector_type(2)));

__device__ __forceinline__ unsigned int umax2(unsigned int a, unsigned int b) {
    u16x2 x = __builtin_bit_cast(u16x2, a), y = __builtin_bit_cast(u16x2, b);
#if defined(__has_builtin) && __has_builtin(__builtin_elementwise_max)
    return __builtin_bit_cast(unsigned int, __builtin_elementwise_max(x, y));  // v_pk_max_u16
#else
    u16x2 r; r.x = x.x > y.x ? x.x : y.x; r.y = x.y > y.y ? x.y : y.y;
    return __builtin_bit_cast(unsigned int, r);
#endif
}
__device__ __forceinline__ float frcp(float x) {
#if defined(__has_builtin) && __has_builtin(__builtin_amdgcn_rcpf)
    return __builtin_amdgcn_rcpf(x);
#else
    return 1.0f / x;
#endif
}
__device__ __forceinline__ unsigned short f2bf(float f) {   // RNE f32->bf16
    unsigned int u = __builtin_bit_cast(unsigned int, f);
    return (unsigned short)((u + 0x7fffu + ((u >> 16) & 1u)) >> 16);
}
__device__ __forceinline__ float bf2f(unsigned short b) {
    return __builtin_bit_cast(float, (unsigned int)b << 16);
}
// NaN-killing sanitizer (fmaxf(NaN,lo)=lo on AMD): result always in [lo,hi], never NaN.
__device__ __forceinline__ float sane(float x, float lo, float hi) {
    return fminf(fmaxf(x, lo), hi);
}
__device__ __forceinline__ int pk2_fp8(float a, float b) {
#if defined(__has_builtin) && __has_builtin(__builtin_amdgcn_cvt_pk_fp8_f32)
    return __builtin_amdgcn_cvt_pk_fp8_f32(a, b, 0, false);
#else
    __hip_fp8_e4m3 A(a), B(b);
    return (int)A.__x | ((int)B.__x << 8);
#endif
}
// exact max byte (u8) over 8 dwords of positive-e4m3 bytes, via even/odd u16 lanes
__device__ __forceinline__ unsigned int bmax8(u32x4 a, u32x4 b) {
    const unsigned int M = 0x00FF00FFu;
    unsigned int l0 = umax2(a.x & M, a.y & M), l1 = umax2(a.z & M, a.w & M);
    unsigned int l2 = umax2(b.x & M, b.y & M), l3 = umax2(b.z & M, b.w & M);
    unsigned int h0 = umax2((a.x >> 8) & M, (a.y >> 8) & M);
    unsigned int h1 = umax2((a.z >> 8) & M, (a.w >> 8) & M);
    unsigned int h2 = umax2((b.x >> 8) & M, (b.y >> 8) & M);
    unsigned int h3 = umax2((b.z >> 8) & M, (b.w >> 8) & M);
    unsigned int v = umax2(umax2(umax2(l0, l1), umax2(l2, l3)),
                           umax2(umax2(h0, h1), umax2(h2, h3)));
    u16x2 t = __builtin_bit_cast(u16x2, v);
    return (unsigned int)(t.x > t.y ? t.x : t.y);
}
__device__ __forceinline__ float fp8dec(unsigned int bb) {   // e4m3 byte -> float
    bb &= 0x7Fu;
    int e = (int)(bb >> 3), mt = (int)(bb & 7u);
    float v = e ? __builtin_ldexpf((float)(8 + mt), e - 10)
                : __builtin_ldexpf((float)mt, -9);
    return sane(v, 1e-9f, 448.f);
}

// ws layout (bytes)
#define WS_QF   0        // fp8 seam q_kf   [256][128]
#define WS_QB   32768    // fp8 seam u_kf+1 [256][128]
#define WS_SF   65536    // float Sf[256]
#define WS_SB   66560    // float Sb[256]
#define WS_G    67584    // float gold[256]
#define WS_RES  68608    // float res[256]
#define WS_CNT  69632    // int cnt[256]   (memset 0)
#define WS_DONE 70656    // int done       (memset 0)

// r13 = r12 + FUSED JOIN: forward/backward chains in separate 4-wave blocks (512 blocks);
// per-row arrival counter (device-scope atomic + threadfence) lets the SECOND-arriving
// block of each pair do the join in-kernel with its own operator:
//   fwd joiner: (E^T q).u ; bwd joiner: q.(E u) — both = q^T E u (algebra-checked).
// A global done-counter makes the last joiner sum all 256 rows and write out directly
// -> launch list shrinks to {2KB memset, kernel}. Hot loop unchanged from r12
// (fp8 state, 2x mfma_scale_16x16x128/wave, exact u8-hint max, 1 barrier/step,
// emit half-slice bf16 in LDS, VMEM-free).
__global__ __launch_bounds__(256, 1) void k_scan3(
        const float* __restrict__ emit, const int* __restrict__ labels,
        const void* __restrict__ masks, const float* __restrict__ T,
        unsigned char* __restrict__ ws, float* __restrict__ out) {
    const int b   = blockIdx.x & (BATCH - 1);
    const int dir = blockIdx.x >> 8;         // 0 = forward, 1 = backward
    const int tid = threadIdx.x;
    const int w = tid >> 6;                  // wave 0..3
    const int lane = tid & 63;
    const int g = lane >> 4, m = lane & 15;  // quad (k-chunk), col
    const int ja = 32 * w + m, jb = ja + 16; // this wave's two output labels

    __shared__ unsigned short elds[255][L];              // emit rows (this dir's half)
    __shared__ __align__(16) unsigned char qs[2][L];     // state, double-buffered
    __shared__ __align__(8)  unsigned char hb[2][4];     // hint bytes [buf][quad]
    __shared__ float part[4];
    __shared__ float fsx[4];
    __shared__ int   ib[4];
    __shared__ int   arriv;

    // ---- init block-shared state + mask encoding self-detect (first 8KB) ----
    {
        const unsigned int* mw0 = (const unsigned int*)masks;
        int pred = 0;
        #pragma unroll
        for (int k = 0; k < 8; ++k) {
            unsigned int w0 = mw0[tid + 256 * k];
            pred |= (w0 > 1u && w0 != 0x3f800000u);
        }
        unsigned long long bal = __ballot(pred);
        if (lane == 0) ib[w] = (bal != 0ull) ? 1 : 0;
        if (tid < 8)   ((unsigned char*)hb)[tid] = 0x38;   // fp8(1.0)
        if (tid < 256) ((unsigned char*)qs)[tid] = 0x38;   // both buffers = 1.0
        if (tid < 4)   { part[tid] = 0.f; fsx[tid] = 0.f; }
    }
    __syncthreads();
    const bool isbyte = (ib[0] | ib[1] | ib[2] | ib[3]) != 0;

    // ---- len of row b (prefix-ones mask; per-wave redundant, uniform) ----
    int len;
    {
        int cnt = 0;
        if (isbyte) {
            const unsigned int* mw = (const unsigned int*)masks + b * (S_LEN / 4);
            #pragma unroll
            for (int k = 0; k < 2; ++k) {
                unsigned int w0 = mw[lane + 64 * k];
                cnt += ((w0 & 0xffu) != 0) + ((w0 & 0xff00u) != 0) +
                       ((w0 & 0xff0000u) != 0) + ((w0 & 0xff000000u) != 0);
            }
        } else {
            const unsigned int* mw = (const unsigned int*)masks + b * S_LEN;
            #pragma unroll
            for (int k = 0; k < 8; ++k) cnt += (mw[lane + 64 * k] != 0u);
        }
        #pragma unroll
        for (int off = 32; off; off >>= 1) cnt += __shfl_xor(cnt, off, 64);
        len = cnt;
    }
    const int n  = len - 1;
    const int kf = n / 2;                    // forward steps
    const int nB = n - kf - 1;               // backward steps (may be <0 for n=0)
    const int steps = dir ? (nB > 0 ? nB : 0) : kf;

    // ---- B-frags: byte slot s = 32g+4d+y, j(s) = 16*(s&7)+(s>>3).
    //      forward (E^T matvec): B[s][col] = expT[j(s)][col]
    //      backward (E matvec):  B[s][col] = expT[col][j(s)] ----
#define LDBX(BF, nt, TR)                                                                     \
    {                                                                                        \
        _Pragma("unroll")                                                                    \
        for (int d = 0; d < 8; ++d) {                                                        \
            int s0 = 32 * g + 4 * d;                                                         \
            float v0, v1, v2, v3;                                                            \
            if (TR) {                                                                        \
                v0 = __expf(T[(16 * (nt) + m) * L + (16 * ((s0 + 0) & 7) + ((s0 + 0) >> 3))]); \
                v1 = __expf(T[(16 * (nt) + m) * L + (16 * ((s0 + 1) & 7) + ((s0 + 1) >> 3))]); \
                v2 = __expf(T[(16 * (nt) + m) * L + (16 * ((s0 + 2) & 7) + ((s0 + 2) >> 3))]); \
                v3 = __expf(T[(16 * (nt) + m) * L + (16 * ((s0 + 3) & 7) + ((s0 + 3) >> 3))]); \
            } else {                                                                         \
                v0 = __expf(T[(16 * ((s0 + 0) & 7) + ((s0 + 0) >> 3)) * L + 16 * (nt) + m]);   \
                v1 = __expf(T[(16 * ((s0 + 1) & 7) + ((s0 + 1) >> 3)) * L + 16 * (nt) + m]);   \
                v2 = __expf(T[(16 * ((s0 + 2) & 7) + ((s0 + 2) >> 3)) * L + 16 * (nt) + m]);   \
                v3 = __expf(T[(16 * ((s0 + 3) & 7) + ((s0 + 3) >> 3)) * L + 16 * (nt) + m]);   \
            }                                                                                \
            int p01 = pk2_fp8(v0, v1), p23 = pk2_fp8(v2, v3);                                \
            BF[d] = (p01 & 0xffff) | (p23 << 16);                                            \
        }                                                                                    \
    }
    i32x8 Bq0, Bq1;
    if (dir == 0) { LDBX(Bq0, 2 * w, 0) LDBX(Bq1, 2 * w + 1, 0) }
    else          { LDBX(Bq0, 2 * w, 1) LDBX(Bq1, 2 * w + 1, 1) }

    // ---- stage this dir's emit rows into LDS as bf16 (coalesced float2->b32) ----
    for (int idx = tid; idx < steps * 64; idx += 256) {
        int rl = idx >> 6, c2 = (idx & 63) * 2;
        int row = dir ? (kf + 1 + rl) : (1 + rl);
        const float* ep = emit + ((size_t)row * BATCH + b) * L + c2;
        float e0 = ep[0], e1 = ep[1];
        *(unsigned int*)&elds[rl][c2] =
            (unsigned int)f2bf(e0) | ((unsigned int)f2bf(e1) << 16);
    }

    // ---- init state: fwd q0 (emit row 0); bwd u_n = x_n o w (emit row n, exact) ----
    float fa = 0.f, fbv = 0.f;
    const bool active = (dir == 0) || (n >= 1);
    if (dir == 0) {
        fa  = emit[b * L + ja] + T[START_ID * L + ja];
        fbv = emit[b * L + jb] + T[START_ID * L + jb];
    } else if (n >= 1) {
        fa  = emit[((size_t)n * BATCH + b) * L + ja] + T[ja * L + PAD_ID];
        fbv = emit[((size_t)n * BATCH + b) * L + jb] + T[jb * L + PAD_ID];
    }
    {
        float mx = fmaxf(fa, fbv);
        #pragma unroll
        for (int off = 32; off; off >>= 1) mx = fmaxf(mx, __shfl_xor(mx, off, 64));
        if (lane == 0) fsx[w] = mx;
    }
    __syncthreads();   // also makes staged emit visible
    float S = 0.f, p0 = 0.f, p1 = 0.f;
    if (active) {
        S = fmaxf(fmaxf(fsx[0], fsx[1]), fmaxf(fsx[2], fsx[3]));
        p0 = sane(__expf(fa - S), 1e-9f, 400.f);
        p1 = sane(__expf(fbv - S), 1e-9f, 400.f);
        if (g == 0)
            *(short*)&qs[0][8 * m + 2 * w] = (short)(pk2_fp8(p0, p1) & 0xffff);
    }
    __syncthreads();

    // ---- hot loop (r9 step, 4-wave barrier) ----
    const f32x4 z = {0.f, 0.f, 0.f, 0.f};
    for (int i = 0; i < steps; ++i) {
        const int rb = i & 1, wb2 = (i + 1) & 1;
        const int slot = dir ? (nB - 1 - i) : i;

        i32x4 alo = *(const i32x4*)&qs[rb][32 * g];
        i32x4 ahi = *(const i32x4*)&qs[rb][32 * g + 16];
        unsigned int hd = *(const unsigned int*)&hb[rb][0];
        float ea = bf2f(elds[slot][ja]);
        float eb = bf2f(elds[slot][jb]);
        float xe0 = __expf(ea), xe1 = __expf(eb);

        {   // uniform max of the 4 hint bytes (exact max of all 128 state bytes)
            const unsigned int M = 0x00FF00FFu;
            unsigned int v = umax2(hd & M, (hd >> 8) & M);
            u16x2 tv = __builtin_bit_cast(u16x2, v);
            hd = (unsigned int)(tv.x > tv.y ? tv.x : tv.y);
        }
        float msc = fp8dec(hd);
        float kk = frcp(msc);

        i32x8 A;
        A[0] = alo[0]; A[1] = alo[1]; A[2] = alo[2]; A[3] = alo[3];
        A[4] = ahi[0]; A[5] = ahi[1]; A[6] = ahi[2]; A[7] = ahi[3];

        f32x4 c0 = __builtin_amdgcn_mfma_scale_f32_16x16x128_f8f6f4(A, Bq0, z, 0, 0, 0, 127, 0, 127);
        f32x4 c1 = __builtin_amdgcn_mfma_scale_f32_16x16x128_f8f6f4(A, Bq1, z, 0, 0, 0, 127, 0, 127);

        unsigned int qm = bmax8(__builtin_bit_cast(u32x4, alo),
                                __builtin_bit_cast(u32x4, ahi));
        if (w == 0 && m == 0) hb[wb2][g] = (unsigned char)(qm & 0x7Fu);

        p0 = sane(c0[0] * kk * xe0, 1e-9f, 400.f);   // rows replicated: c[0] valid
        p1 = sane(c1[0] * kk * xe1, 1e-9f, 400.f);
        if (g == 0)
            *(short*)&qs[wb2][8 * m + 2 * w] = (short)(pk2_fp8(p0, p1) & 0xffff);
        S += __logf(msc);
        __syncthreads();
    }

    // ---- release: seam + scale (+ gold for fwd) -> ws, then per-row arrival ----
    unsigned char* seam = ws + (dir ? WS_QB : WS_QF) + b * L;
    if (tid < 32) ((int*)seam)[tid] = ((const int*)qs[steps & 1])[tid];
    if (tid == 0) ((float*)(ws + (dir ? WS_SB : WS_SF)))[b] = S;

    float gold = 0.f;
    if (dir == 0) {
        float gsum = 0.f;
        for (int tt = tid; tt < len; tt += 256) {
            int nxt = labels[b * S_LEN + tt];
            int prv = tt ? labels[b * S_LEN + tt - 1] : START_ID;
            gsum += emit[((size_t)tt * BATCH + b) * L + nxt] + T[prv * L + nxt];
            if (tt == len - 1) gsum += T[nxt * L + PAD_ID];
        }
        #pragma unroll
        for (int off = 32; off; off >>= 1) gsum += __shfl_xor(gsum, off, 64);
        if (lane == 0) part[w] = gsum;
        __syncthreads();
        gold = (part[0] + part[1]) + (part[2] + part[3]);
        if (tid == 0) ((float*)(ws + WS_G))[b] = gold;
    }

    __threadfence();                                     // release seam/S/gold
    if (tid == 0) arriv = atomicAdd((int*)(ws + WS_CNT) + b, 1);
    __syncthreads();
    if (arriv != 1) return;                              // first arriver exits

    // ---- JOIN (second arriver; other dir's data acquired) ----
    __threadfence();
    float ev = 0.f;
    if (n >= 1) {
        // own-operator matvec of OWN state (still in LDS), dotted with other's seam:
        // fwd: (E^T q).u ; bwd: q.(E u) — both equal q^T E u.
        const unsigned char* oseam = ws + (dir ? WS_QF : WS_QB) + b * L;
        i32x4 alo = *(const i32x4*)&qs[steps & 1][32 * g];
        i32x4 ahi = *(const i32x4*)&qs[steps & 1][32 * g + 16];
        i32x8 A;
        A[0] = alo[0]; A[1] = alo[1]; A[2] = alo[2]; A[3] = alo[3];
        A[4] = ahi[0]; A[5] = ahi[1]; A[6] = ahi[2]; A[7] = ahi[3];
        f32x4 c0 = __builtin_amdgcn_mfma_scale_f32_16x16x128_f8f6f4(A, Bq0, z, 0, 0, 0, 127, 0, 127);
        f32x4 c1 = __builtin_amdgcn_mfma_scale_f32_16x16x128_f8f6f4(A, Bq1, z, 0, 0, 0, 127, 0, 127);
        if (g == 0) {
            float o0 = fp8dec(oseam[8 * m + 2 * w]);
            float o1 = fp8dec(oseam[8 * m + 2 * w + 1]);
            ev = sane(c0[0], 0.f, 3e7f) * o0 + sane(c1[0], 0.f, 3e7f) * o1;
        }
    } else {
        // n==0: enc = Sf + log(sum_j q0_j expT[j][PAD]); q0 own (fwd) or fwd seam (bwd)
        if (g == 0) {
            float q0 = (dir == 0) ? p0 : fp8dec(ws[WS_QF + b * L + 8 * m + 2 * w]);
            float q1 = (dir == 0) ? p1 : fp8dec(ws[WS_QF + b * L + 8 * m + 2 * w + 1]);
            ev = q0 * __expf(T[ja * L + PAD_ID]) + q1 * __expf(T[jb * L + PAD_ID]);
        }
    }
    #pragma unroll
    for (int off = 32; off; off >>= 1) ev += __shfl_xor(ev, off, 64);
    if (lane == 0) part[w] = ev;
    __syncthreads();
    float evtot = fmaxf((part[0] + part[1]) + (part[2] + part[3]), 1e-35f);

    float Sf = ((const float*)(ws + WS_SF))[b];
    float Sb = (n >= 1) ? ((const float*)(ws + WS_SB))[b] : 0.f;
    float enc = Sf + Sb + __logf(evtot);
    if (dir == 1) gold = ((const float*)(ws + WS_G))[b];

    if (tid == 0) {
        ((float*)(ws + WS_RES))[b] = sane(enc - gold, -1e30f, 1e30f);
        __threadfence();                                 // release res[b]
        arriv = atomicAdd((int*)(ws + WS_DONE), 1);
    }
    __syncthreads();
    if (arriv == BATCH - 1) {                            // last row done: final sum
        __threadfence();
        if (tid < 64) {
            const float* res = (const float*)(ws + WS_RES);
            float s = (res[tid] + res[tid + 64]) + (res[tid + 128] + res[tid + 192]);
            #pragma unroll
            for (int off = 32; off; off >>= 1) s += __shfl_xor(s, off, 64);
            if (tid == 0) out[0] = s;
        }
    }
}

extern "C" void kernel_launch(void* const* d_in, const int* in_sizes, int n_in,
                              void* d_out, int out_size, void* d_ws, size_t ws_size,
                              hipStream_t stream) {
    const float* emit   = (const float*)d_in[0];
    const int*   labels = (const int*)d_in[1];
    const void*  masks  = d_in[2];
    const float* T      = (const float*)d_in[3];
    float* out = (float*)d_out;
    unsigned char* ws = (unsigned char*)d_ws;

    hipMemsetAsync(ws + WS_CNT, 0, 2048, stream);        // cnt[256] + done
    k_scan3<<<dim3(2 * BATCH), dim3(256), 0, stream>>>(emit, labels, masks, T, ws, out);
}